// Round 2
// 4771.614 us; speedup vs baseline: 1.3799x; 1.3799x over previous
//
#include <hip/hip_runtime.h>
#include <hip/hip_bf16.h>
#include <stdint.h>

typedef __attribute__((ext_vector_type(8))) short bf16x8;
typedef __attribute__((ext_vector_type(4))) float floatx4;

// Problem constants
#define TT 512
#define BB 64
#define DD 1024
#define HH 1024
#define YS_ELEMS 33554432UL  // TT*BB*HH

// ws layout (bytes)
#define OFF_A     0UL           // A[n][m] col-major bf16: 4096*32768*2 = 256 MiB
#define OFF_XB    268435456UL   // x bf16 [32768][1024]
#define OFF_WIT   335544320UL   // WiT bf16 [4096][1024]
#define OFF_WHT   343932928UL   // WhT bf16 [4096][1024]
#define OFF_HBUF  352321536UL   // 2 x [64][1024] bf16
#define OFF_FLAGS 352583680UL   // 64 flags, 64B stride

#define NBLK 64
#define WPITCH 2064
#define LDSW_BYTES (64 * WPITCH)                   // 132096
#define LDSR_FLOATS (2 * 64 * 33)                  // 4224 floats (pad 33 -> conflict-free)
#define SMEM_BYTES (LDSW_BYTES + LDSR_FLOATS * 4)  // 148992 < 160 KiB

__device__ __forceinline__ unsigned short f2bf(float f) {
  union { float f; unsigned u; } v; v.f = f;
  unsigned r = (v.u + 0x7fffu + ((v.u >> 16) & 1u)) >> 16;
  return (unsigned short)r;
}
__device__ __forceinline__ float bf2f(unsigned short s) {
  union { unsigned u; float f; } v; v.u = ((unsigned)s) << 16;
  return v.f;
}
__device__ __forceinline__ float sigm(float x) { return 1.0f / (1.0f + __expf(-x)); }
__device__ __forceinline__ float tanh_fast(float x) { return 1.0f - 2.0f / (1.0f + __expf(2.0f * x)); }
__device__ __forceinline__ float ap_get(uint2 p, int r) {
  unsigned u = (r < 2) ? p.x : p.y;
  return bf2f((unsigned short)(u >> ((r & 1) * 16)));
}
__device__ __forceinline__ void gload_lds16(const void* g, void* l) {
  __builtin_amdgcn_global_load_lds((const __attribute__((address_space(1))) void*)g,
                                   (__attribute__((address_space(3))) void*)l, 16, 0, 0);
}
// ---- Infinity-Cache-coherent (bypass L1+L2) asm memory ops ----
__device__ __forceinline__ bf16x8 ldg_b128_if(const void* p) {
  bf16x8 v;
  asm volatile("global_load_dwordx4 %0, %1, off sc0 sc1"
               : "=v"(v) : "v"(p) : "memory");
  return v;
}
__device__ __forceinline__ int ldg_b32_if(const void* p) {
  int v;
  asm volatile("global_load_dword %0, %1, off sc0 sc1\n\ts_waitcnt vmcnt(0)"
               : "=v"(v) : "v"(p) : "memory");
  return v;
}
__device__ __forceinline__ void stg_b64_if(void* p, uint2 v) {
  asm volatile("global_store_dwordx2 %0, %1, off sc0 sc1"
               :: "v"(p), "v"(v) : "memory");
}
__device__ __forceinline__ void stg_b32_if(void* p, int v) {
  asm volatile("global_store_dword %0, %1, off sc0 sc1"
               :: "v"(p), "v"(v) : "memory");
}

// ---------------- fp32 -> bf16 convert (x and h0) ----------------
__global__ void convert_kernel(const float* __restrict__ x, const float* __restrict__ h0,
                               unsigned short* __restrict__ xb, unsigned short* __restrict__ hb0) {
  const long total4 = (33554432L + 65536L) / 4;
  long stride = (long)gridDim.x * blockDim.x;
  for (long i = (long)blockIdx.x * blockDim.x + threadIdx.x; i < total4; i += stride) {
    long base = i * 4;
    const float4* src;
    unsigned short* dst;
    if (base < 33554432L) { src = (const float4*)(x + base); dst = xb + base; }
    else { src = (const float4*)(h0 + (base - 33554432L)); dst = hb0 + (base - 33554432L); }
    float4 v = *src;
    uint2 p;
    p.x = (unsigned)f2bf(v.x) | ((unsigned)f2bf(v.y) << 16);
    p.y = (unsigned)f2bf(v.z) | ((unsigned)f2bf(v.w) << 16);
    *(uint2*)dst = p;
  }
}

// ---------------- transpose W [1024][4096] fp32 -> WT [4096][1024] bf16 ----------------
__global__ void transpose_kernel(const float* __restrict__ W, unsigned short* __restrict__ WT) {
  __shared__ float tile[32][33];
  int n0 = blockIdx.x * 32, k0 = blockIdx.y * 32;
  int tx = threadIdx.x & 31, ty = threadIdx.x >> 5;
#pragma unroll
  for (int r = 0; r < 4; r++)
    tile[ty + r * 8][tx] = W[(size_t)(k0 + ty + r * 8) * 4096 + n0 + tx];
  __syncthreads();
#pragma unroll
  for (int r = 0; r < 4; r++)
    WT[(size_t)(n0 + ty + r * 8) * 1024 + k0 + tx] = f2bf(tile[tx][ty + r * 8]);
}

// ---------------- Phase 1: A[m][n] = x@Wi + b, stored col-major A[n][m] bf16 ----------------
__global__ __launch_bounds__(256) void gemm1_kernel(const unsigned short* __restrict__ xb,
                                                    const unsigned short* __restrict__ wiT,
                                                    const float* __restrict__ bias,
                                                    unsigned short* __restrict__ Aws) {
  __shared__ unsigned short ldsA[128 * 32];
  __shared__ unsigned short ldsB[128 * 32];
  int id = blockIdx.x;
  int xcd = id & 7, seq = id >> 3;
  int n0 = (xcd * 4 + (seq & 3)) * 128;
  int m0 = (seq >> 2) * 128;
  int tid = threadIdx.x, w = tid >> 6, l = tid & 63;
  int wm = w & 1, wn = w >> 1;
  int c = l & 15, q = l >> 4;
  const floatx4 fz = {0.f, 0.f, 0.f, 0.f};
  floatx4 acc[4][4];
#pragma unroll
  for (int mi = 0; mi < 4; mi++)
#pragma unroll
    for (int ni = 0; ni < 4; ni++) acc[mi][ni] = fz;

  const char* gA = (const char*)xb + (size_t)(m0 + w * 32 + (l >> 2)) * 2048 + (l & 3) * 16;
  const char* gB = (const char*)wiT + (size_t)(n0 + w * 32 + (l >> 2)) * 2048 + (l & 3) * 16;
  char* lA = (char*)ldsA + (w * 32) * 64;
  char* lB = (char*)ldsB + (w * 32) * 64;

  for (int kt = 0; kt < 32; kt++) {
    gload_lds16(gA, lA);
    gload_lds16(gA + 16 * 2048, lA + 16 * 64);
    gload_lds16(gB, lB);
    gload_lds16(gB + 16 * 2048, lB + 16 * 64);
    gA += 64; gB += 64;
    __syncthreads();
    bf16x8 a[4], b[4];
#pragma unroll
    for (int mi = 0; mi < 4; mi++)
      a[mi] = *(const bf16x8*)((const char*)ldsA + (wm * 64 + mi * 16 + c) * 64 + q * 16);
#pragma unroll
    for (int ni = 0; ni < 4; ni++)
      b[ni] = *(const bf16x8*)((const char*)ldsB + (wn * 64 + ni * 16 + c) * 64 + q * 16);
#pragma unroll
    for (int mi = 0; mi < 4; mi++)
#pragma unroll
      for (int ni = 0; ni < 4; ni++)
        acc[mi][ni] = __builtin_amdgcn_mfma_f32_16x16x32_bf16(a[mi], b[ni], acc[mi][ni], 0, 0, 0);
    __syncthreads();
  }
#pragma unroll
  for (int mi = 0; mi < 4; mi++) {
#pragma unroll
    for (int ni = 0; ni < 4; ni++) {
      int n_g = n0 + wn * 64 + ni * 16 + c;
      float bn = bias[n_g];
      size_t mbase = (size_t)m0 + wm * 64 + mi * 16 + q * 4;
      floatx4 v = acc[mi][ni];
      uint2 p;
      p.x = (unsigned)f2bf(v.x + bn) | ((unsigned)f2bf(v.y + bn) << 16);
      p.y = (unsigned)f2bf(v.z + bn) | ((unsigned)f2bf(v.w + bn) << 16);
      *(uint2*)((char*)Aws + (((size_t)n_g << 15) + mbase) * 2) = p;
    }
  }
}

// ---------------- Phase 2: persistent recurrent kernel, 64 blocks ----------------
// Sync protocol unchanged (IF-coherent sc0sc1 h/flags, double-buffered hbuf).
// Step structure:
//   - split-K: wave (wi,wj) computes K-half wj for ALL 4 gates (halves h traffic
//     and halves per-wave load count); partials reduced once via padded LDS.
//   - all 32 h loads issued up front, counted vmcnt(30-2kt) + sched_barrier(0).
//   - wj0 computes all gates, packs h via shfl_xor, publishes h+flag EARLY;
//     out/cT/hT stores deferred until after the flag.
__global__ __launch_bounds__(256, 1) void lstm_kernel(const unsigned short* __restrict__ Aws,
                                                      const unsigned short* __restrict__ whT,
                                                      const float* __restrict__ c0,
                                                      unsigned short* __restrict__ hbuf,
                                                      float* __restrict__ out,
                                                      int* __restrict__ flags) {
  extern __shared__ char smem[];
  char* ldsW = smem;                           // 64 rows * WPITCH
  float* ldsR = (float*)(smem + LDSW_BYTES);   // [2][64][33] partial-acc exchange
  int tid = threadIdx.x, wid = tid >> 6, l = tid & 63;
  int wi = wid & 1, wj = wid >> 1;
  int c = l & 15, q = l >> 4;
  int hbase = blockIdx.x * 16;

  // stage WhT slice into LDS once
  for (int i = tid; i < 64 * 128; i += 256) {
    int ln = i >> 7, ch = i & 127;
    int n_g = (ln >> 4) * 1024 + hbase + (ln & 15);
    *(uint4*)(ldsW + ln * WPITCH + ch * 16) =
        *(const uint4*)((const char*)whT + (size_t)n_g * 2048 + ch * 16);
  }
  float cst[2][4];
  if (wj == 0) {
#pragma unroll
    for (int mi = 0; mi < 2; mi++)
#pragma unroll
      for (int r = 0; r < 4; r++)
        cst[mi][r] = c0[(wi * 32 + mi * 16 + q * 4 + r) * 1024 + hbase + c];
  }
  __syncthreads();

  for (int t = 0; t < 512; t++) {
    // A-slice prefetch (cached loads; only wj0 consumes A)
    uint2 ap[2][4];
    if (wj == 0) {
#pragma unroll
      for (int mi = 0; mi < 2; mi++)
#pragma unroll
        for (int nj = 0; nj < 4; nj++) {
          size_t n_g = (size_t)nj * 1024 + hbase + c;
          ap[mi][nj] = *(const uint2*)((const char*)Aws +
                        ((n_g << 15) + (size_t)t * 64 + wi * 32 + mi * 16 + q * 4) * 2);
        }
    }

    // wave 0 (wj0,wi0): poll flags (IF-coherent loads)
    if (wid == 0) {
      const char* fp_ = (const char*)(flags + l * 16);
      int probes = 0;
      for (;;) {
        int v = ldg_b32_if(fp_);
        if (__all(v >= t)) break;
        if (((++probes) & 2047) == 0)  // safety valve only
          (void)__hip_atomic_load(&flags[l * 16], __ATOMIC_ACQUIRE, __HIP_MEMORY_SCOPE_AGENT);
      }
    }
    __syncthreads();
    // clean vmcnt slate: deferred out-stores / ap loads drained under the poll
    asm volatile("s_waitcnt vmcnt(0)" ::: "memory");

    // K-loop: wave (wi,wj) loads rows wi*32+c / +16, K-half wj.  All 32 loads
    // issued up front (one IF latency instead of four at depth 16).
    const char* hp = (const char*)hbuf + (size_t)(t & 1) * 131072;
    const char* ha0 = hp + (size_t)(wi * 32 + c) * 2048 + wj * 1024 + q * 16;
    const char* ha1 = ha0 + 16 * 2048;
    bf16x8 pf0[16], pf1[16];
#pragma unroll
    for (int kt = 0; kt < 16; kt++) {
      pf0[kt] = ldg_b128_if(ha0 + kt * 64);
      pf1[kt] = ldg_b128_if(ha1 + kt * 64);
    }
    const floatx4 fz = {0.f, 0.f, 0.f, 0.f};
    floatx4 acc[2][4];
#pragma unroll
    for (int mi = 0; mi < 2; mi++)
#pragma unroll
      for (int nj = 0; nj < 4; nj++) acc[mi][nj] = fz;

#pragma unroll
    for (int kt = 0; kt < 16; kt++) {
      bf16x8 b0 = *(const bf16x8*)(ldsW + (0 * 16 + c) * WPITCH + wj * 1024 + kt * 64 + q * 16);
      bf16x8 b1 = *(const bf16x8*)(ldsW + (1 * 16 + c) * WPITCH + wj * 1024 + kt * 64 + q * 16);
      bf16x8 b2 = *(const bf16x8*)(ldsW + (2 * 16 + c) * WPITCH + wj * 1024 + kt * 64 + q * 16);
      bf16x8 b3 = *(const bf16x8*)(ldsW + (3 * 16 + c) * WPITCH + wj * 1024 + kt * 64 + q * 16);
      asm volatile("s_waitcnt vmcnt(%0)" :: "n"(30 - 2 * kt) : "memory");
      __builtin_amdgcn_sched_barrier(0);
      acc[0][0] = __builtin_amdgcn_mfma_f32_16x16x32_bf16(pf0[kt], b0, acc[0][0], 0, 0, 0);
      acc[0][1] = __builtin_amdgcn_mfma_f32_16x16x32_bf16(pf0[kt], b1, acc[0][1], 0, 0, 0);
      acc[0][2] = __builtin_amdgcn_mfma_f32_16x16x32_bf16(pf0[kt], b2, acc[0][2], 0, 0, 0);
      acc[0][3] = __builtin_amdgcn_mfma_f32_16x16x32_bf16(pf0[kt], b3, acc[0][3], 0, 0, 0);
      acc[1][0] = __builtin_amdgcn_mfma_f32_16x16x32_bf16(pf1[kt], b0, acc[1][0], 0, 0, 0);
      acc[1][1] = __builtin_amdgcn_mfma_f32_16x16x32_bf16(pf1[kt], b1, acc[1][1], 0, 0, 0);
      acc[1][2] = __builtin_amdgcn_mfma_f32_16x16x32_bf16(pf1[kt], b2, acc[1][2], 0, 0, 0);
      acc[1][3] = __builtin_amdgcn_mfma_f32_16x16x32_bf16(pf1[kt], b3, acc[1][3], 0, 0, 0);
    }

    // cross-wave K-reduction: wj1 dumps partials, wj0 reduces
    if (wj == 1) {
      float* p = ldsR + (size_t)(wi * 64 + l) * 33;
#pragma unroll
      for (int mi = 0; mi < 2; mi++)
#pragma unroll
        for (int nj = 0; nj < 4; nj++)
#pragma unroll
          for (int r = 0; r < 4; r++)
            p[mi * 16 + nj * 4 + r] = acc[mi][nj][r];
    }
    __syncthreads();

    float hreg[2][4], cnl[2][4];
    if (wj == 0) {
      const float* p = ldsR + (size_t)(wi * 64 + l) * 33;
#pragma unroll
      for (int mi = 0; mi < 2; mi++) {
#pragma unroll
        for (int r = 0; r < 4; r++) {
          float zi = acc[mi][0][r] + p[mi * 16 + 0 + r] + ap_get(ap[mi][0], r);
          float zf = acc[mi][1][r] + p[mi * 16 + 4 + r] + ap_get(ap[mi][1], r);
          float zg = acc[mi][2][r] + p[mi * 16 + 8 + r] + ap_get(ap[mi][2], r);
          float zo = acc[mi][3][r] + p[mi * 16 + 12 + r] + ap_get(ap[mi][3], r);
          float ig = sigm(zi), fg = sigm(zf);
          float tg = tanh_fast(zg), og = sigm(zo);
          float cn = fg * cst[mi][r] + ig * tg;
          cst[mi][r] = cn;
          cnl[mi][r] = cn;
          hreg[mi][r] = og * tanh_fast(cn);
        }
      }
      // publish h ASAP: pack 4 cols/lane via shfl_xor, IF-coherent b64 stores
      if (t < 511) {
        unsigned short* hn = hbuf + (size_t)(1 - (t & 1)) * 65536;
#pragma unroll
        for (int mi = 0; mi < 2; mi++)
#pragma unroll
          for (int r = 0; r < 4; r++) {
            unsigned hb = (unsigned)f2bf(hreg[mi][r]);
            unsigned p1 = (unsigned)__shfl_xor((int)hb, 1);
            unsigned lo = (hb & 0xffffu) | (p1 << 16);   // valid on even-c lanes
            unsigned lo2 = (unsigned)__shfl_xor((int)lo, 2);
            if ((c & 3) == 0) {
              uint2 pk; pk.x = lo; pk.y = lo2;           // cols c..c+3
              int row = wi * 32 + mi * 16 + q * 4 + r;
              stg_b64_if((char*)(hn + (size_t)row * 1024 + hbase + c), pk);
            }
          }
        asm volatile("s_waitcnt vmcnt(0)" ::: "memory");  // h acked at IF
      }
    }
    __syncthreads();  // wj0 waves' h stores committed before flag
    if (t < 511 && tid == 0)
      stg_b32_if(flags + blockIdx.x * 16, t + 1);

    // deferred output stores (off the inter-block critical path)
    if (wj == 0) {
#pragma unroll
      for (int mi = 0; mi < 2; mi++)
#pragma unroll
        for (int r = 0; r < 4; r++) {
          int row = wi * 32 + mi * 16 + q * 4 + r;
          out[(size_t)t * 65536 + (size_t)row * 1024 + hbase + c] = hreg[mi][r];
          if (t == 511) {
            out[YS_ELEMS + (size_t)row * 1024 + hbase + c] = cnl[mi][r];          // cT
            out[YS_ELEMS + 65536 + (size_t)row * 1024 + hbase + c] = hreg[mi][r]; // hT
          }
        }
    }
  }
}

extern "C" void kernel_launch(void* const* d_in, const int* in_sizes, int n_in,
                              void* d_out, int out_size, void* d_ws, size_t ws_size,
                              hipStream_t stream) {
  (void)in_sizes; (void)n_in; (void)out_size; (void)ws_size;
  const float* x  = (const float*)d_in[0];
  const float* c0 = (const float*)d_in[1];
  const float* h0 = (const float*)d_in[2];
  const float* Wi = (const float*)d_in[3];
  const float* Wh = (const float*)d_in[4];
  const float* b  = (const float*)d_in[5];
  float* out = (float*)d_out;
  char* ws = (char*)d_ws;
  unsigned short* Aws  = (unsigned short*)(ws + OFF_A);
  unsigned short* xb   = (unsigned short*)(ws + OFF_XB);
  unsigned short* wiT  = (unsigned short*)(ws + OFF_WIT);
  unsigned short* whT  = (unsigned short*)(ws + OFF_WHT);
  unsigned short* hbuf = (unsigned short*)(ws + OFF_HBUF);
  int* flags = (int*)(ws + OFF_FLAGS);

  hipMemsetAsync(flags, 0, 4096, stream);
  convert_kernel<<<4096, 256, 0, stream>>>(x, h0, xb, hbuf);
  transpose_kernel<<<dim3(128, 32), 256, 0, stream>>>(Wi, wiT);
  transpose_kernel<<<dim3(128, 32), 256, 0, stream>>>(Wh, whT);
  gemm1_kernel<<<8192, 256, 0, stream>>>(xb, wiT, b, Aws);
  lstm_kernel<<<NBLK, 256, SMEM_BYTES, stream>>>(Aws, whT, c0, hbuf, out, flags);
}